// Round 11
// baseline (234.811 us; speedup 1.0000x reference)
//
#include <hip/hip_runtime.h>
#include <stdint.h>

#define IN_CH 128
#define HID   64
#define NREL  8

typedef __attribute__((ext_vector_type(8))) short bf16x8;
typedef __attribute__((ext_vector_type(4))) float f32x4;
typedef __attribute__((ext_vector_type(2))) float f32x2;

__device__ __forceinline__ unsigned short f2bf(float f) {
  union { float f; unsigned u; } v; v.f = f;
  unsigned r = v.u + 0x7fffu + ((v.u >> 16) & 1u);   // RN-even
  return (unsigned short)(r >> 16);
}

// ---------------------------------------------------------------------------
// k_prep: Wt[r][o][k] = bf16(W[r][k][o]);  also detect used_mask elem width.
// ---------------------------------------------------------------------------
__global__ __launch_bounds__(256) void k_prep(const float* __restrict__ W,
                                              const unsigned char* __restrict__ um,
                                              unsigned short* __restrict__ Wt,
                                              int* __restrict__ flag, int total) {
  int t = blockIdx.x * 256 + threadIdx.x;
  if (t < total) {
    int r = t >> 13;            // / (128*64)
    int rem = t & 8191;
    int o = rem >> 7;           // / 128
    int k = rem & 127;
    Wt[t] = f2bf(W[(r << 13) + k * HID + o]);
  }
  if (blockIdx.x == 0 && threadIdx.x < 64) {
    unsigned w = ((const unsigned*)um)[threadIdx.x];   // first 256 bytes
    int s = (int)((w & 0xffu) + ((w >> 8) & 0xffu) + ((w >> 16) & 0xffu) + ((w >> 24) & 0xffu));
#pragma unroll
    for (int m = 1; m < 64; m <<= 1) s += __shfl_xor(s, m);
    if (threadIdx.x == 0) *flag = (s > 150) ? 1 : 0;   // 1 => bytes, 0 => int32
  }
}

// ---------------------------------------------------------------------------
// k_gemm v5: xW8[n][r*64+o] = fp8_e4m3( used(n) * sum_k x[n][k]*W[r][k][o] )
// Identical structure to v4 (persistent per-relation W in registers, 8 waves,
// double-buffered XOR-swizzled LDS staging of x, mask folded at staging,
// fp8 output).  Only change: 1024 persistent blocks (4/CU, was 2/CU) to
// double TLP over the per-tile load->sync->MFMA latency chain.
// ---------------------------------------------------------------------------
__global__ __launch_bounds__(512) void k_gemm(const float* __restrict__ x,
                                              const unsigned short* __restrict__ Wt,
                                              unsigned char* __restrict__ xW,
                                              const void* __restrict__ um,
                                              const int* __restrict__ flagp,
                                              int ntiles, int N) {
  __shared__ unsigned short lds[2][16 * IN_CH];     // 2 x 4 KB
  int w    = threadIdx.x >> 6;                      // wave id == relation
  int lane = threadIdx.x & 63;
  int l15  = lane & 15;
  int kg   = lane >> 4;

  // one-time: this wave's relation W fragments -> registers
  bf16x8 wf[16];
  {
    const unsigned short* wb = Wt + ((size_t)(w * HID + l15)) * IN_CH + kg * 8;
#pragma unroll
    for (int ot = 0; ot < 4; ++ot)
#pragma unroll
      for (int ki = 0; ki < 4; ++ki)
        wf[ot * 4 + ki] = *(const bf16x8*)(wb + (ot * 16) * IN_CH + ki * 32);
  }

  int bytes = *flagp;
  const unsigned char* um8 = (const unsigned char*)um;
  const int* um32 = (const int*)um;

  int node_s = threadIdx.x >> 5;                    // staging: node in tile
  int q      = threadIdx.x & 31;                    // float4 index in row
  int wboff  = node_s * 256 + ((q * 8) ^ ((node_s & 7) << 4));  // swizzled 8B
  int rswz   = (l15 & 7) << 4;                      // read-side swizzle

  int stride = gridDim.x;
  int t = blockIdx.x;
  if (t >= ntiles) return;                          // uniform per block

  // prologue: load + stage tile t into buf 0
  float4 pre; float mpre;
  {
    int n = t * 16 + node_s;
    int nc = n < N ? n : N - 1;
    pre = *(const float4*)(x + (size_t)nc * IN_CH + q * 4);
    mpre = (bytes ? (int)um8[nc] : um32[nc]) != 0 ? 1.0f : 0.0f;
    ushort4 b;
    b.x = f2bf(pre.x * mpre); b.y = f2bf(pre.y * mpre);
    b.z = f2bf(pre.z * mpre); b.w = f2bf(pre.w * mpre);
    *(ushort4*)((char*)(&lds[0][0]) + wboff) = b;
  }

  int buf = 0;
  for (; t < ntiles; t += stride) {
    int tn = t + stride;
    bool has_next = tn < ntiles;
    if (has_next) {                                 // issue early: latency
      int n = tn * 16 + node_s;                     // hides under compute
      int nc = n < N ? n : N - 1;
      pre = *(const float4*)(x + (size_t)nc * IN_CH + q * 4);
      mpre = (bytes ? (int)um8[nc] : um32[nc]) != 0 ? 1.0f : 0.0f;
    }
    __syncthreads();                                // lds[buf] ready
    bf16x8 xf[4];
    const char* lbase = (const char*)(&lds[buf][0]);
#pragma unroll
    for (int ki = 0; ki < 4; ++ki) {
      int c = (kg * 16 + ki * 64) ^ rswz;
      xf[ki] = *(const bf16x8*)(lbase + l15 * 256 + c);
    }
    int node = t * 16 + l15;
    bool st = node < N;
    size_t orow = (size_t)node * (NREL * HID) + w * HID + kg * 4;
#pragma unroll
    for (int ot = 0; ot < 4; ++ot) {
      f32x4 acc = {0.f, 0.f, 0.f, 0.f};
#pragma unroll
      for (int ki = 0; ki < 4; ++ki)
        acc = __builtin_amdgcn_mfma_f32_16x16x32_bf16(wf[ot * 4 + ki], xf[ki], acc, 0, 0, 0);
      if (st) {
        int p = __builtin_amdgcn_cvt_pk_fp8_f32(acc[0], acc[1], 0, false);
        p = __builtin_amdgcn_cvt_pk_fp8_f32(acc[2], acc[3], p, true);
        *(unsigned*)(xW + orow + ot * 16) = (unsigned)p;
      }
    }
    if (has_next) {                                 // write-late: load landed
      ushort4 b;
      b.x = f2bf(pre.x * mpre); b.y = f2bf(pre.y * mpre);
      b.z = f2bf(pre.z * mpre); b.w = f2bf(pre.w * mpre);
      *(ushort4*)((char*)(&lds[buf ^ 1][0]) + wboff) = b;
    }
    buf ^= 1;
  }
}

// ---------------------------------------------------------------------------
// k_agg v5: pure gather-sum over fp8 xW.  One wave per node; lane =
// (g = edge subgroup 0..7, c8 = chan oct 0..7).  Each lane gathers 8 B
// (2 dwords = 8 fp8 chans) per edge; 8 lanes cover the 64 B row.  Halves
// per-lane gather + meta instruction count vs v4 (VALU-issue relief);
// row fetch traffic is line-granular and unchanged.
// ---------------------------------------------------------------------------
__global__ __launch_bounds__(256) void k_agg(const unsigned char* __restrict__ xW,
                                             const int* __restrict__ ptr,
                                             const int* __restrict__ idx,
                                             const int* __restrict__ et,
                                             const int* __restrict__ hmap,
                                             const float* __restrict__ hbuf,
                                             const int* __restrict__ hszp,
                                             float* __restrict__ out, int N) {
  int wid = (int)((blockIdx.x * 256u + threadIdx.x) >> 6);
  if (wid >= N) return;
  int lane = threadIdx.x & 63;
  int g = lane >> 3, c8 = lane & 7;
  size_t orow = (size_t)wid * HID + (size_t)c8 * 8;

  int hs = *hszp;
  int hm = hmap[wid];
  if (hs > 0 && hm != -1) {                  // history override: skip gather
    if (g == 0) {
      float4 h0 = *(const float4*)(hbuf + orow);
      float4 h1 = *(const float4*)(hbuf + orow + 4);
      *(float4*)(out + orow) = h0;
      *(float4*)(out + orow + 4) = h1;
    }
    return;
  }

  int e0 = ptr[wid], e1 = ptr[wid + 1];

  float a[8] = {0.f, 0.f, 0.f, 0.f, 0.f, 0.f, 0.f, 0.f};
  for (int base = e0; base < e1; base += 32) {
    int src[4], rel[4];
    float ok[4];
#pragma unroll
    for (int j = 0; j < 4; ++j) {            // phase 1: metadata (independent)
      int e = base + g + j * 8;
      bool v = e < e1;
      int ee = v ? e : e0;                   // e0 < e1 here, so in-bounds
      src[j] = idx[ee];
      rel[j] = et[ee];
      ok[j] = v ? 1.0f : 0.0f;
    }
    uint2 vv[4];
#pragma unroll
    for (int j = 0; j < 4; ++j) {            // phase 2: 8B gathers (indep)
      int rc = rel[j] & (NREL - 1);
      vv[j] = *(const uint2*)(xW + (size_t)src[j] * (NREL * HID) + rc * HID + c8 * 8);
    }
#pragma unroll
    for (int j = 0; j < 4; ++j) {            // phase 3: decode + accumulate
      f32x2 p0 = __builtin_amdgcn_cvt_pk_f32_fp8((int)vv[j].x, false);
      f32x2 p1 = __builtin_amdgcn_cvt_pk_f32_fp8((int)vv[j].x, true);
      f32x2 p2 = __builtin_amdgcn_cvt_pk_f32_fp8((int)vv[j].y, false);
      f32x2 p3 = __builtin_amdgcn_cvt_pk_f32_fp8((int)vv[j].y, true);
      a[0] += ok[j] * p0[0]; a[1] += ok[j] * p0[1];
      a[2] += ok[j] * p1[0]; a[3] += ok[j] * p1[1];
      a[4] += ok[j] * p2[0]; a[5] += ok[j] * p2[1];
      a[6] += ok[j] * p3[0]; a[7] += ok[j] * p3[1];
    }
  }
#pragma unroll
  for (int m = 8; m < 64; m <<= 1) {
#pragma unroll
    for (int c = 0; c < 8; ++c) a[c] += __shfl_xor(a[c], m);
  }
  if (g == 0) {
    int deg = e1 - e0;
    float inv = deg > 0 ? 1.0f / (float)deg : 0.0f;
    float4 o0, o1;
    o0.x = a[0] * inv; o0.y = a[1] * inv; o0.z = a[2] * inv; o0.w = a[3] * inv;
    o1.x = a[4] * inv; o1.y = a[5] * inv; o1.z = a[6] * inv; o1.w = a[7] * inv;
    *(float4*)(out + orow) = o0;
    *(float4*)(out + orow + 4) = o1;
  }
}

// ---------------------------------------------------------------------------
extern "C" void kernel_launch(void* const* d_in, const int* in_sizes, int n_in,
                              void* d_out, int out_size, void* d_ws, size_t ws_size,
                              hipStream_t stream) {
  const float* x  = (const float*)d_in[0];
  const float* W  = (const float*)d_in[1];
  const float* hb = (const float*)d_in[2];
  const int* ptr  = (const int*)d_in[3];
  const int* idx  = (const int*)d_in[4];
  const int* et   = (const int*)d_in[5];
  // d_in[6] = count (unused)
  const int* hmap = (const int*)d_in[7];
  const void* um  = d_in[8];
  const int* hsz  = (const int*)d_in[9];
  int N = in_sizes[3] - 1;
  float* out = (float*)d_out;

  // ws layout: [0,128KB) Wt bf16 ; [128KB,+4) flag ; [1MB, +N*512) xW fp8
  unsigned short* Wt = (unsigned short*)d_ws;
  int* flag = (int*)((char*)d_ws + 131072);
  unsigned char* xW = (unsigned char*)d_ws + (1 << 20);

  int totW = NREL * IN_CH * HID;                 // 65536
  k_prep<<<(totW + 255) / 256, 256, 0, stream>>>(W, (const unsigned char*)um, Wt, flag, totW);

  int ntiles = (N + 15) / 16;
  int gblocks = ntiles < 1024 ? ntiles : 1024;   // 4 blocks/CU, grid-stride
  k_gemm<<<gblocks, 512, 0, stream>>>(x, Wt, xW, um, flag, ntiles, N);

  long long athreads = (long long)N * 64;
  k_agg<<<(int)((athreads + 255) / 256), 256, 0, stream>>>(xW, ptr, idx, et, hmap, hb,
                                                           hsz, out, N);
}

// Round 12
// 213.541 us; speedup vs baseline: 1.0996x; 1.0996x over previous
//
#include <hip/hip_runtime.h>
#include <stdint.h>

#define IN_CH 128
#define HID   64
#define NREL  8

typedef __attribute__((ext_vector_type(8))) short bf16x8;
typedef __attribute__((ext_vector_type(4))) float f32x4;
typedef __attribute__((ext_vector_type(2))) float f32x2;

__device__ __forceinline__ unsigned short f2bf(float f) {
  union { float f; unsigned u; } v; v.f = f;
  unsigned r = v.u + 0x7fffu + ((v.u >> 16) & 1u);   // RN-even
  return (unsigned short)(r >> 16);
}

// ---------------------------------------------------------------------------
// k_prep: Wt[r][p][k] = bf16(W[r][k][chan(p)]) — fragment-ordered rows so
// k_gemm's per-lane ot-dwords land CONTIGUOUS in xW (chan(p) below is the
// inverse of store position p = ot*16 + kg*4 + j -> chan kg*16 + ot*4 + j).
// Also detects used_mask elem width.
// ---------------------------------------------------------------------------
__global__ __launch_bounds__(256) void k_prep(const float* __restrict__ W,
                                              const unsigned char* __restrict__ um,
                                              unsigned short* __restrict__ Wt,
                                              int* __restrict__ flag, int total) {
  int t = blockIdx.x * 256 + threadIdx.x;
  if (t < total) {
    int r = t >> 13;            // / (128*64)
    int p = (t >> 7) & 63;      // fragment row position
    int k = t & 127;
    int o = (((p >> 2) & 3) << 4) + (((p >> 4) & 3) << 2) + (p & 3);  // chan
    Wt[t] = f2bf(W[(r << 13) + (k << 6) + o]);
  }
  if (blockIdx.x == 0 && threadIdx.x < 64) {
    unsigned w = ((const unsigned*)um)[threadIdx.x];   // first 256 bytes
    int s = (int)((w & 0xffu) + ((w >> 8) & 0xffu) + ((w >> 16) & 0xffu) + ((w >> 24) & 0xffu));
#pragma unroll
    for (int m = 1; m < 64; m <<= 1) s += __shfl_xor(s, m);
    if (threadIdx.x == 0) *flag = (s > 150) ? 1 : 0;   // 1 => bytes, 0 => int32
  }
}

// ---------------------------------------------------------------------------
// k_gemm v6: xW8[n][r*64+c] = fp8_e4m3( used(n) * sum_k x[n][k]*W[r][k][c] )
// 8 waves (wave==relation, persistent W frags in 64 VGPR).  4 tiles (64
// nodes) per step: one barrier per 64 nodes (was per 16), 2x16KB LDS dbuf,
// 16 float4 loads in flight per thread.  Stores: via k_prep's row permute,
// each lane packs 4 ot-dwords -> ONE uint4 (16B) store; 4 kg-lanes cover the
// full 64B (node,rel) row coalesced (was 16 scattered 4B dwords).
// ---------------------------------------------------------------------------
__global__ __launch_bounds__(512) void k_gemm(const float* __restrict__ x,
                                              const unsigned short* __restrict__ Wt,
                                              unsigned char* __restrict__ xW,
                                              const void* __restrict__ um,
                                              const int* __restrict__ flagp,
                                              int nsteps, int N) {
  __shared__ unsigned short lds[2][64 * IN_CH];     // 2 x 16 KB
  int w    = threadIdx.x >> 6;                      // wave id == relation
  int lane = threadIdx.x & 63;
  int l15  = lane & 15;
  int kg   = lane >> 4;

  // one-time: this wave's relation W fragments -> registers
  bf16x8 wf[16];
  {
    const unsigned short* wb = Wt + ((size_t)(w * HID + l15)) * IN_CH + kg * 8;
#pragma unroll
    for (int ot = 0; ot < 4; ++ot)
#pragma unroll
      for (int ki = 0; ki < 4; ++ki)
        wf[ot * 4 + ki] = *(const bf16x8*)(wb + (ot * 16) * IN_CH + ki * 32);
  }

  int bytes = *flagp;
  const unsigned char* um8 = (const unsigned char*)um;
  const int* um32 = (const int*)um;

  int node_s = threadIdx.x >> 5;                    // staging row 0..15
  int q      = threadIdx.x & 31;                    // float4 index in row
  int wboff  = node_s * 256 + ((q * 8) ^ ((node_s & 7) << 4));  // swizzled 8B
  int rswz   = (l15 & 7) << 4;                      // read-side swizzle

  int stride = gridDim.x;
  int t = blockIdx.x;
  if (t >= nsteps) return;                          // uniform per block

  // prologue: load + stage step t into buf 0 (4 sub-rows per thread)
  float4 pre[4]; float mpre[4];
#pragma unroll
  for (int j = 0; j < 4; ++j) {
    int n = t * 64 + node_s + j * 16;
    int nc = n < N ? n : N - 1;
    pre[j] = *(const float4*)(x + (size_t)nc * IN_CH + q * 4);
    mpre[j] = (bytes ? (int)um8[nc] : um32[nc]) != 0 ? 1.0f : 0.0f;
  }
#pragma unroll
  for (int j = 0; j < 4; ++j) {
    ushort4 b;
    b.x = f2bf(pre[j].x * mpre[j]); b.y = f2bf(pre[j].y * mpre[j]);
    b.z = f2bf(pre[j].z * mpre[j]); b.w = f2bf(pre[j].w * mpre[j]);
    *(ushort4*)((char*)(&lds[0][0]) + wboff + j * 4096) = b;
  }

  int buf = 0;
  for (; t < nsteps; t += stride) {
    int tn = t + stride;
    bool has_next = tn < nsteps;
    if (has_next) {                                 // issue early
#pragma unroll
      for (int j = 0; j < 4; ++j) {
        int n = tn * 64 + node_s + j * 16;
        int nc = n < N ? n : N - 1;
        pre[j] = *(const float4*)(x + (size_t)nc * IN_CH + q * 4);
        mpre[j] = (bytes ? (int)um8[nc] : um32[nc]) != 0 ? 1.0f : 0.0f;
      }
    }
    __syncthreads();                                // lds[buf] ready
#pragma unroll
    for (int s = 0; s < 4; ++s) {                   // 4 sub-tiles, no barrier
      const char* lbase = (const char*)(&lds[buf][0]) + s * 4096;
      bf16x8 xf[4];
#pragma unroll
      for (int ki = 0; ki < 4; ++ki)
        xf[ki] = *(const bf16x8*)(lbase + l15 * 256 + ((kg * 16 + ki * 64) ^ rswz));
      int node = t * 64 + s * 16 + l15;
      bool st = node < N;
      unsigned pdw[4];
#pragma unroll
      for (int ot = 0; ot < 4; ++ot) {
        f32x4 acc = {0.f, 0.f, 0.f, 0.f};
#pragma unroll
        for (int ki = 0; ki < 4; ++ki)
          acc = __builtin_amdgcn_mfma_f32_16x16x32_bf16(wf[ot * 4 + ki], xf[ki], acc, 0, 0, 0);
        int p = __builtin_amdgcn_cvt_pk_fp8_f32(acc[0], acc[1], 0, false);
        p = __builtin_amdgcn_cvt_pk_fp8_f32(acc[2], acc[3], p, true);
        pdw[ot] = (unsigned)p;
      }
      if (st) {
        uint4 v; v.x = pdw[0]; v.y = pdw[1]; v.z = pdw[2]; v.w = pdw[3];
        *(uint4*)(xW + (size_t)node * (NREL * HID) + w * HID + kg * 16) = v;
      }
    }
    if (has_next) {                                 // write-late: loads landed
#pragma unroll
      for (int j = 0; j < 4; ++j) {
        ushort4 b;
        b.x = f2bf(pre[j].x * mpre[j]); b.y = f2bf(pre[j].y * mpre[j]);
        b.z = f2bf(pre[j].z * mpre[j]); b.w = f2bf(pre[j].w * mpre[j]);
        *(ushort4*)((char*)(&lds[buf ^ 1][0]) + wboff + j * 4096) = b;
      }
    }
    buf ^= 1;
  }
}

// ---------------------------------------------------------------------------
// k_agg v5 (unchanged — at structural floor: line-bound random gather).
// One wave per node; lane = (g = edge subgroup 0..7, c8 = chan oct 0..7);
// 8 B gathers, mask pre-folded into xW, history-hit nodes skip.
// ---------------------------------------------------------------------------
__global__ __launch_bounds__(256) void k_agg(const unsigned char* __restrict__ xW,
                                             const int* __restrict__ ptr,
                                             const int* __restrict__ idx,
                                             const int* __restrict__ et,
                                             const int* __restrict__ hmap,
                                             const float* __restrict__ hbuf,
                                             const int* __restrict__ hszp,
                                             float* __restrict__ out, int N) {
  int wid = (int)((blockIdx.x * 256u + threadIdx.x) >> 6);
  if (wid >= N) return;
  int lane = threadIdx.x & 63;
  int g = lane >> 3, c8 = lane & 7;
  size_t orow = (size_t)wid * HID + (size_t)c8 * 8;

  int hs = *hszp;
  int hm = hmap[wid];
  if (hs > 0 && hm != -1) {                  // history override: skip gather
    if (g == 0) {
      float4 h0 = *(const float4*)(hbuf + orow);
      float4 h1 = *(const float4*)(hbuf + orow + 4);
      *(float4*)(out + orow) = h0;
      *(float4*)(out + orow + 4) = h1;
    }
    return;
  }

  int e0 = ptr[wid], e1 = ptr[wid + 1];

  float a[8] = {0.f, 0.f, 0.f, 0.f, 0.f, 0.f, 0.f, 0.f};
  for (int base = e0; base < e1; base += 32) {
    int src[4], rel[4];
    float ok[4];
#pragma unroll
    for (int j = 0; j < 4; ++j) {            // phase 1: metadata (independent)
      int e = base + g + j * 8;
      bool v = e < e1;
      int ee = v ? e : e0;                   // e0 < e1 here, so in-bounds
      src[j] = idx[ee];
      rel[j] = et[ee];
      ok[j] = v ? 1.0f : 0.0f;
    }
    uint2 vv[4];
#pragma unroll
    for (int j = 0; j < 4; ++j) {            // phase 2: 8B gathers (indep)
      int rc = rel[j] & (NREL - 1);
      vv[j] = *(const uint2*)(xW + (size_t)src[j] * (NREL * HID) + rc * HID + c8 * 8);
    }
#pragma unroll
    for (int j = 0; j < 4; ++j) {            // phase 3: decode + accumulate
      f32x2 p0 = __builtin_amdgcn_cvt_pk_f32_fp8((int)vv[j].x, false);
      f32x2 p1 = __builtin_amdgcn_cvt_pk_f32_fp8((int)vv[j].x, true);
      f32x2 p2 = __builtin_amdgcn_cvt_pk_f32_fp8((int)vv[j].y, false);
      f32x2 p3 = __builtin_amdgcn_cvt_pk_f32_fp8((int)vv[j].y, true);
      a[0] += ok[j] * p0[0]; a[1] += ok[j] * p0[1];
      a[2] += ok[j] * p1[0]; a[3] += ok[j] * p1[1];
      a[4] += ok[j] * p2[0]; a[5] += ok[j] * p2[1];
      a[6] += ok[j] * p3[0]; a[7] += ok[j] * p3[1];
    }
  }
#pragma unroll
  for (int m = 8; m < 64; m <<= 1) {
#pragma unroll
    for (int c = 0; c < 8; ++c) a[c] += __shfl_xor(a[c], m);
  }
  if (g == 0) {
    int deg = e1 - e0;
    float inv = deg > 0 ? 1.0f / (float)deg : 0.0f;
    float4 o0, o1;
    o0.x = a[0] * inv; o0.y = a[1] * inv; o0.z = a[2] * inv; o0.w = a[3] * inv;
    o1.x = a[4] * inv; o1.y = a[5] * inv; o1.z = a[6] * inv; o1.w = a[7] * inv;
    *(float4*)(out + orow) = o0;
    *(float4*)(out + orow + 4) = o1;
  }
}

// ---------------------------------------------------------------------------
extern "C" void kernel_launch(void* const* d_in, const int* in_sizes, int n_in,
                              void* d_out, int out_size, void* d_ws, size_t ws_size,
                              hipStream_t stream) {
  const float* x  = (const float*)d_in[0];
  const float* W  = (const float*)d_in[1];
  const float* hb = (const float*)d_in[2];
  const int* ptr  = (const int*)d_in[3];
  const int* idx  = (const int*)d_in[4];
  const int* et   = (const int*)d_in[5];
  // d_in[6] = count (unused)
  const int* hmap = (const int*)d_in[7];
  const void* um  = d_in[8];
  const int* hsz  = (const int*)d_in[9];
  int N = in_sizes[3] - 1;
  float* out = (float*)d_out;

  // ws layout: [0,128KB) Wt bf16 ; [128KB,+4) flag ; [1MB, +N*512) xW fp8
  unsigned short* Wt = (unsigned short*)d_ws;
  int* flag = (int*)((char*)d_ws + 131072);
  unsigned char* xW = (unsigned char*)d_ws + (1 << 20);

  int totW = NREL * IN_CH * HID;                 // 65536
  k_prep<<<(totW + 255) / 256, 256, 0, stream>>>(W, (const unsigned char*)um, Wt, flag, totW);

  int nsteps = (N + 63) / 64;                    // 64-node steps
  int gblocks = nsteps < 512 ? nsteps : 512;     // 2 blocks/CU, grid-stride
  k_gemm<<<gblocks, 512, 0, stream>>>(x, Wt, xW, um, flag, nsteps, N);

  long long athreads = (long long)N * 64;
  k_agg<<<(int)((athreads + 255) / 256), 256, 0, stream>>>(xW, ptr, idx, et, hmap, hb,
                                                           hsz, out, N);
}